// Round 9
// baseline (323.002 us; speedup 1.0000x reference)
//
#include <hip/hip_runtime.h>

#define K_DIM 8192
#define M_REAL 2000
#define N_REAL 2000
#define M_PAD 2048
#define N_PAD 2048

#define BM 128
#define BN 128
#define BK 32
#define SPLITK 2
#define KSLAB (K_DIM / SPLITK)   // 4096
#define NSTEP (KSLAB / BK)       // 128 K-steps per block

typedef __bf16 bf16x8 __attribute__((ext_vector_type(8)));
typedef float f32x4 __attribute__((ext_vector_type(4)));
typedef float fvec4 __attribute__((ext_vector_type(4)));

__device__ __forceinline__ unsigned short f2bf(float f) {
    union { float f; unsigned u; } v; v.f = f;
    unsigned r = v.u + 0x7FFFu + ((v.u >> 16) & 1u);  // RNE; inputs are finite normals
    return (unsigned short)(r >> 16);
}

__device__ __forceinline__ unsigned pk2(float a, float b) {
    return (unsigned)f2bf(a) | ((unsigned)f2bf(b) << 16);
}

__device__ __forceinline__ void async16(const void* g, void* l) {
    __builtin_amdgcn_global_load_lds((__attribute__((address_space(1))) void*)(g),
                                     (__attribute__((address_space(3))) void*)(l),
                                     16, 0, 0);
}

// ---------------------------------------------------------------------------
// prep_x: X [8192][2000] f32 -> XT bf16 [2048][8192] transpose (n>=2000 zero).
// Conflict-free LDS (row stride 65 words === 1 mod 32). [R1-verified path]
__global__ __launch_bounds__(256) void prep_x(const float* __restrict__ X,
                                              unsigned short* __restrict__ XT) {
    __shared__ unsigned short T[64][130];
    int b = blockIdx.x;
    int k0 = (b & 63) << 7;        // 0..8064 step 128
    int n0 = (b >> 6) << 6;        // 0..1984 step 64
    int t = threadIdx.x;
    int c = t & 15;
    int r = t >> 4;
    int nl = c << 2;               // local n base (x4)
    int n = n0 + nl;
    bool valid = (n < N_REAL);
#pragma unroll
    for (int p = 0; p < 4; ++p) {
        int kl = (r << 1) + (p << 5);
        fvec4 v0 = {0.f, 0.f, 0.f, 0.f};
        fvec4 v1 = {0.f, 0.f, 0.f, 0.f};
        if (valid) {
            v0 = __builtin_nontemporal_load((const fvec4*)(X + (k0 + kl) * N_REAL + n));
            v1 = __builtin_nontemporal_load((const fvec4*)(X + (k0 + kl + 1) * N_REAL + n));
        }
        *(unsigned*)&T[nl + 0][kl] = pk2(v0.x, v1.x);
        *(unsigned*)&T[nl + 1][kl] = pk2(v0.y, v1.y);
        *(unsigned*)&T[nl + 2][kl] = pk2(v0.z, v1.z);
        *(unsigned*)&T[nl + 3][kl] = pk2(v0.w, v1.w);
    }
    __syncthreads();
#pragma unroll
    for (int it = 0; it < 4; ++it) {
        int nl2 = r + (it << 4);
        int kl2 = c << 3;
        const unsigned* tp = (const unsigned*)&T[nl2][kl2];
        uint4 o;
        o.x = tp[0]; o.y = tp[1]; o.z = tp[2]; o.w = tp[3];
        *(uint4*)(XT + (((n0 + nl2) << 13) + k0 + kl2)) = o;
    }
}

// ---------------------------------------------------------------------------
// R8b GEMM (R8 with the workspace overflow fixed via SPLITK=2):
// R6's K-loop (128^2 tile, BK=32, 256 thr / 4 waves, 2-deep LDS 32 KiB,
// syncthreads-drain, 0-conflict T2 swizzle) with:
//   (1) A-side fused conversion: reg-stage W f32 -> pk2 -> swizzled
//       ds_write_b128 (T14: loads for step s+2 issued at step s, cvt+write
//       at s+1). Deletes prep_w, freeing 33.5 MB of workspace.
//   (2) Epilogue: unguarded coalesced stores to part[bz][2048][2048] f32
//       (pad written, never read) -- NO atomics. Isolates the atomic cost.
// Workspace: XT 33.5 MB + part[2] 33.5 MB = 67 MB = the footprint proven
// safe since R0 (R8's 100.7 MB was the likely container-kill).
__global__ __launch_bounds__(256, 4) void gemm_kernel(const float* __restrict__ W,
                                                      const unsigned short* __restrict__ XT,
                                                      float* __restrict__ part) {
    __shared__ __align__(16) char smA[2 * 8192];   // 2 x (128 rows x 64 B)
    __shared__ __align__(16) char smB[2 * 8192];

    int f = blockIdx.x;                    // 0..511
    int xcd = f & 7;
    int local = f >> 3;                    // 0..63
    int bz = local & 1;
    int lt = local >> 1;                   // 0..31
    int bx = (xcd & 3) * 4 + (lt & 3);     // 0..15
    int by = (xcd >> 2) * 8 + (lt >> 2);   // 0..15

    int t = threadIdx.x;
    int w = t >> 6;                // 0..3
    int l = t & 63;
    int lane16 = l & 15;
    int quad = l >> 4;
    int wr = w >> 1;               // 0..1  (m-half)
    int wc = w & 1;                // 0..1  (n-half)
    int m0 = by * BM;
    int n0 = bx * BN;
    int ks = bz * KSLAB;

    f32x4 acc[4][4] = {};
    const fvec4 z4 = {0.f, 0.f, 0.f, 0.f};

    // ---- A fused-conversion staging map ----
    // thread t -> row rA = t>>1 (0..127), k-half hA = t&1 (16 f32 = 64 B read).
    // LDS row = 64 B = 4 chunks; logical chunks {2hA, 2hA+1}; phys = lc ^ swA,
    // swA = (rA>>1)&3  [matches reader swizzle, R4-verified 0-conflict].
    int rA = t >> 1;
    int hA = t & 1;
    int rowA = m0 + rA;
    bool aValid = (rowA < M_REAL);
    const float* gW = W + (long long)(aValid ? rowA : 0) * K_DIM + ks + hA * 16;
    int swA = (rA >> 1) & 3;
    int dA0 = rA * 64 + (((hA << 1) | 0) ^ swA) * 16;   // byte offset in one buf
    int dA1 = rA * 64 + (((hA << 1) | 1) ^ swA) * 16;

    fvec4 wreg0, wreg1, wreg2, wreg3;

#define LOADA(S) do { \
        const float* p_ = gW + (S) * BK; \
        wreg0 = *(const fvec4*)(p_); \
        wreg1 = *(const fvec4*)(p_ + 4); \
        wreg2 = *(const fvec4*)(p_ + 8); \
        wreg3 = *(const fvec4*)(p_ + 12); \
        if (!aValid) { wreg0 = z4; wreg1 = z4; wreg2 = z4; wreg3 = z4; } \
    } while (0)

#define WRITEA(BUF) do { \
        int bo_ = (BUF) * 8192; \
        uint4 u0, u1; \
        u0.x = pk2(wreg0.x, wreg0.y); u0.y = pk2(wreg0.z, wreg0.w); \
        u0.z = pk2(wreg1.x, wreg1.y); u0.w = pk2(wreg1.z, wreg1.w); \
        u1.x = pk2(wreg2.x, wreg2.y); u1.y = pk2(wreg2.z, wreg2.w); \
        u1.z = pk2(wreg3.x, wreg3.y); u1.w = pk2(wreg3.z, wreg3.w); \
        *(uint4*)(smA + bo_ + dA0) = u0; \
        *(uint4*)(smA + bo_ + dA1) = u1; \
    } while (0)

    // ---- B staging (async16, pre-swizzled source, linear dest) as R6 ----
    int rowS = w * 32 + (l >> 2);                  // +0 (call0) / +16 (call1)
    int lc   = (l & 3) ^ ((l >> 3) & 3);
    const unsigned short* gB0 = XT + (long long)(n0 + rowS) * K_DIM + ks + lc * 8;
    const unsigned short* gB1 = gB0 + 16LL * K_DIM;

#define STAGEB(BUF, KOFF) do { \
        int bo_ = (BUF) * 8192 + w * 2048; \
        async16(gB0 + (KOFF), smB + bo_); \
        async16(gB1 + (KOFF), smB + bo_ + 1024); \
    } while (0)

    // ---- reader-side swizzled row offsets ----
    int swz = ((quad ^ ((lane16 >> 1) & 3)) << 4);
    int arow = (wr * 64 + lane16) * 64 + swz;
    int brow = (wc * 64 + lane16) * 64 + swz;

    // ---- prologue: tile 0 into buf0; A-regs for tile 1 ----
    LOADA(0);
    WRITEA(0);
    LOADA(1);
    STAGEB(0, 0);
    __syncthreads();

    for (int s = 0; s < NSTEP; ++s) {
        if (s + 1 < NSTEP) {
            STAGEB((s + 1) & 1, (s + 1) * BK);
            WRITEA((s + 1) & 1);           // regs loaded at step s-1
        }
        if (s + 2 < NSTEP)
            LOADA(s + 2);                  // lands under this step's MFMAs

        int bo = (s & 1) * 8192;
        const char* Ab = smA + bo + arow;
        const char* Bb = smB + bo + brow;
        bf16x8 a0 = *(const bf16x8*)(Ab);
        bf16x8 a1 = *(const bf16x8*)(Ab + 1024);
        bf16x8 a2 = *(const bf16x8*)(Ab + 2048);
        bf16x8 a3 = *(const bf16x8*)(Ab + 3072);
        bf16x8 b0 = *(const bf16x8*)(Bb);
        bf16x8 b1 = *(const bf16x8*)(Bb + 1024);
        bf16x8 b2 = *(const bf16x8*)(Bb + 2048);
        bf16x8 b3 = *(const bf16x8*)(Bb + 3072);

        acc[0][0] = __builtin_amdgcn_mfma_f32_16x16x32_bf16(a0, b0, acc[0][0], 0, 0, 0);
        acc[0][1] = __builtin_amdgcn_mfma_f32_16x16x32_bf16(a0, b1, acc[0][1], 0, 0, 0);
        acc[0][2] = __builtin_amdgcn_mfma_f32_16x16x32_bf16(a0, b2, acc[0][2], 0, 0, 0);
        acc[0][3] = __builtin_amdgcn_mfma_f32_16x16x32_bf16(a0, b3, acc[0][3], 0, 0, 0);
        acc[1][0] = __builtin_amdgcn_mfma_f32_16x16x32_bf16(a1, b0, acc[1][0], 0, 0, 0);
        acc[1][1] = __builtin_amdgcn_mfma_f32_16x16x32_bf16(a1, b1, acc[1][1], 0, 0, 0);
        acc[1][2] = __builtin_amdgcn_mfma_f32_16x16x32_bf16(a1, b2, acc[1][2], 0, 0, 0);
        acc[1][3] = __builtin_amdgcn_mfma_f32_16x16x32_bf16(a1, b3, acc[1][3], 0, 0, 0);
        acc[2][0] = __builtin_amdgcn_mfma_f32_16x16x32_bf16(a2, b0, acc[2][0], 0, 0, 0);
        acc[2][1] = __builtin_amdgcn_mfma_f32_16x16x32_bf16(a2, b1, acc[2][1], 0, 0, 0);
        acc[2][2] = __builtin_amdgcn_mfma_f32_16x16x32_bf16(a2, b2, acc[2][2], 0, 0, 0);
        acc[2][3] = __builtin_amdgcn_mfma_f32_16x16x32_bf16(a2, b3, acc[2][3], 0, 0, 0);
        acc[3][0] = __builtin_amdgcn_mfma_f32_16x16x32_bf16(a3, b0, acc[3][0], 0, 0, 0);
        acc[3][1] = __builtin_amdgcn_mfma_f32_16x16x32_bf16(a3, b1, acc[3][1], 0, 0, 0);
        acc[3][2] = __builtin_amdgcn_mfma_f32_16x16x32_bf16(a3, b2, acc[3][2], 0, 0, 0);
        acc[3][3] = __builtin_amdgcn_mfma_f32_16x16x32_bf16(a3, b3, acc[3][3], 0, 0, 0);

        if (s + 1 < NSTEP)
            __syncthreads();       // drains vmcnt/lgkm + barrier (R6 semantics)
    }
#undef LOADA
#undef WRITEA
#undef STAGEB

    // Epilogue: unguarded coalesced stores to padded partials. No atomics.
    // C/D layout col = lane&15, row = quad*4 + reg  [m89-verified]
    float* pb = part + ((long long)bz << 22);      // bz * 2048 * 2048
#pragma unroll
    for (int j = 0; j < 4; ++j) {
        int n = n0 + wc * 64 + j * 16 + lane16;
#pragma unroll
        for (int i = 0; i < 4; ++i) {
            int mbase = m0 + wr * 64 + i * 16 + quad * 4;
#pragma unroll
            for (int r = 0; r < 4; ++r)
                pb[(long long)(mbase + r) * 2048 + n] = acc[i][j][r];
        }
    }
}

// ---------------------------------------------------------------------------
// reduce: out[m][n] = part[0][m][n] + part[1][m][n] + bias[n]  (m,n < 2000).
// 2000 blocks (one per row) x 256 thr, f32x4 lanes. ~50 MB -> ~8 us.
__global__ __launch_bounds__(256) void reduce_kernel(const float* __restrict__ part,
                                                     const float* __restrict__ bias,
                                                     float* __restrict__ out) {
    int m = blockIdx.x;
    const float* p0 = part + (long long)m * 2048;
    for (int n4 = threadIdx.x; n4 < N_REAL / 4; n4 += 256) {
        fvec4 s0 = *(const fvec4*)(p0 + n4 * 4);
        fvec4 s1 = *(const fvec4*)(p0 + 4194304 + n4 * 4);
        fvec4 bv = *(const fvec4*)(bias + n4 * 4);
        fvec4 r = s0 + s1 + bv;
        *(fvec4*)(out + (long long)m * N_REAL + n4 * 4) = r;
    }
}

// ---------------------------------------------------------------------------
extern "C" void kernel_launch(void* const* d_in, const int* in_sizes, int n_in,
                              void* d_out, int out_size, void* d_ws, size_t ws_size,
                              hipStream_t stream) {
    const float* W    = (const float*)d_in[0];  // [2000][8192]
    const float* bias = (const float*)d_in[1];  // [2000]
    const float* X    = (const float*)d_in[2];  // [8192][2000]
    float* out = (float*)d_out;

    // workspace: XT bf16 [2048][8192] (33.5 MB) + part f32 [2][2048][2048]
    // (33.5 MB) = 67 MB -- exactly the footprint proven safe since R0.
    unsigned short* XT = (unsigned short*)d_ws;
    float* part = (float*)((char*)d_ws + (size_t)M_PAD * K_DIM * 2);

    prep_x<<<2048, 256, 0, stream>>>(X, XT);
    gemm_kernel<<<(N_PAD / BN) * (M_PAD / BM) * SPLITK, 256, 0, stream>>>(W, XT, part);
    reduce_kernel<<<M_REAL, 256, 0, stream>>>(part, bias, out);
}

// Round 10
// 278.724 us; speedup vs baseline: 1.1589x; 1.1589x over previous
//
#include <hip/hip_runtime.h>

#define K_DIM 8192
#define M_REAL 2000
#define N_REAL 2000
#define M_PAD 2048
#define N_PAD 2048

#define BM 128
#define BN 128
#define BK 32
#define SPLITK 4
#define KSLAB (K_DIM / SPLITK)   // 2048
#define NSTEP (KSLAB / BK)       // 64 K-steps per block

// fused prep block ranges
#define NB_W 1024
#define NB_X 2048
#define NB_I 256

typedef __bf16 bf16x8 __attribute__((ext_vector_type(8)));
typedef float f32x4 __attribute__((ext_vector_type(4)));
typedef float fvec4 __attribute__((ext_vector_type(4)));

#define RAW_BARRIER()  asm volatile("s_barrier" ::: "memory")
#define LGKM0()        asm volatile("s_waitcnt lgkmcnt(0)" ::: "memory")
#define WAIT_VM8()     asm volatile("s_waitcnt vmcnt(8)" ::: "memory")
#define WAIT_VM4()     asm volatile("s_waitcnt vmcnt(4)" ::: "memory")
#define WAIT_VM0()     asm volatile("s_waitcnt vmcnt(0)" ::: "memory")

__device__ __forceinline__ unsigned short f2bf(float f) {
    union { float f; unsigned u; } v; v.f = f;
    unsigned r = v.u + 0x7FFFu + ((v.u >> 16) & 1u);  // RNE; inputs are finite normals
    return (unsigned short)(r >> 16);
}

__device__ __forceinline__ unsigned pk2(float a, float b) {
    return (unsigned)f2bf(a) | ((unsigned)f2bf(b) << 16);
}

__device__ __forceinline__ void async16(const void* g, void* l) {
    __builtin_amdgcn_global_load_lds((__attribute__((address_space(1))) void*)(g),
                                     (__attribute__((address_space(3))) void*)(l),
                                     16, 0, 0);
}

// ---------------------------------------------------------------------------
// Fused prep (one dispatch) — UNCHANGED from R6 (measured near-roofline,
// ~45 us for 212 MB):
//   blocks [0,1024):       W f32 -> Wb bf16 [2048][8192], grid-stride, 32B ld/16B st
//   blocks [1024,3072):    X [8192][2000] f32 -> XT bf16 [2048][8192] transpose,
//                          conflict-free LDS (row stride 65 words === 1 mod 32)
//   blocks [3072,3328):    out[m][n] = bias[n] (float4 stores, grid-stride)
__global__ __launch_bounds__(256) void prep_kernel(const float* __restrict__ W,
                                                   const float* __restrict__ X,
                                                   const float* __restrict__ bias,
                                                   unsigned short* __restrict__ Wb,
                                                   unsigned short* __restrict__ XT,
                                                   float* __restrict__ out) {
    __shared__ unsigned short T[64][130];
    int bid = blockIdx.x;
    if (bid < NB_W) {
        unsigned tid = bid * 256u + threadIdx.x;
#pragma unroll
        for (unsigned i = 0; i < 8; ++i) {
            unsigned e = (i * (1024u * 256u) + tid) * 8u;       // element index
            uint4 o = make_uint4(0u, 0u, 0u, 0u);
            if (e < (unsigned)(M_REAL * K_DIM)) {
                fvec4 f0 = __builtin_nontemporal_load((const fvec4*)(W + e));
                fvec4 f1 = __builtin_nontemporal_load((const fvec4*)(W + e + 4));
                o.x = pk2(f0.x, f0.y);
                o.y = pk2(f0.z, f0.w);
                o.z = pk2(f1.x, f1.y);
                o.w = pk2(f1.z, f1.w);
            }
            *(uint4*)(Wb + e) = o;
        }
    } else if (bid < NB_W + NB_X) {
        int b = bid - NB_W;
        int k0 = (b & 63) << 7;        // 0..8064 step 128
        int n0 = (b >> 6) << 6;        // 0..1984 step 64
        int t = threadIdx.x;
        int c = t & 15;
        int r = t >> 4;
        int nl = c << 2;               // local n base (x4)
        int n = n0 + nl;
        bool valid = (n < N_REAL);
#pragma unroll
        for (int p = 0; p < 4; ++p) {
            int kl = (r << 1) + (p << 5);
            fvec4 v0 = {0.f, 0.f, 0.f, 0.f};
            fvec4 v1 = {0.f, 0.f, 0.f, 0.f};
            if (valid) {
                v0 = __builtin_nontemporal_load((const fvec4*)(X + (k0 + kl) * N_REAL + n));
                v1 = __builtin_nontemporal_load((const fvec4*)(X + (k0 + kl + 1) * N_REAL + n));
            }
            *(unsigned*)&T[nl + 0][kl] = pk2(v0.x, v1.x);
            *(unsigned*)&T[nl + 1][kl] = pk2(v0.y, v1.y);
            *(unsigned*)&T[nl + 2][kl] = pk2(v0.z, v1.z);
            *(unsigned*)&T[nl + 3][kl] = pk2(v0.w, v1.w);
        }
        __syncthreads();
#pragma unroll
        for (int it = 0; it < 4; ++it) {
            int nl2 = r + (it << 4);
            int kl2 = c << 3;
            const unsigned* tp = (const unsigned*)&T[nl2][kl2];
            uint4 o;
            o.x = tp[0]; o.y = tp[1]; o.z = tp[2]; o.w = tp[3];
            *(uint4*)(XT + (((n0 + nl2) << 13) + k0 + kl2)) = o;
        }
    } else {
        const int total = M_REAL * (N_REAL / 4);   // 1,000,000 float4
        for (int i = (bid - NB_W - NB_X) * 256 + (int)threadIdx.x; i < total; i += NB_I * 256) {
            int m = i / (N_REAL / 4);
            int n4 = i - m * (N_REAL / 4);
            float4 bv = *(const float4*)(bias + (n4 << 2));
            *(float4*)(out + m * N_REAL + (n4 << 2)) = bv;
        }
    }
}

// ---------------------------------------------------------------------------
// R10 GEMM: R6's tile/TLP structure + R4's counted-vmcnt ring -- the one
// untried combination. 128^2 tile, BK=32, 256 thr (4 waves, 64x64 wave-tiles),
// 4-deep LDS ring (64 KiB -> 2 blocks/CU; grid 1024 = 2 balanced rounds).
// Step s: stage step s+3 (4 gload_lds), ds_read frags of buf s&3, 16 MFMA,
// then ONE end-of-step {vmcnt(8) | lgkmcnt(0) | s_barrier}. The counted
// vmcnt keeps 8 loads in flight ACROSS the barrier (fixes R6's flaw of
// draining just-issued loads every step); 2 blocks/CU cover what remains
// (fixes R4's 1-block/CU latency exposure).
//
// Ring safety: buffer written at s is (s+3)&3 == (s-1)&3, last read at step
// s-1; reads complete before end-of-(s-1) barrier (LGKM0 precedes it), and
// the writer's stores issue after that barrier. vmcnt(8): the 8 newest loads
// are steps s+2,s+3 -> step s+1's buffer landed. Tail peels VM8->VM4->VM0.
//
// T2 swizzle (R4-verified 0 conflicts): phys chunk = logical ^ ((row>>1)&3),
// applied both sides (pre-swizzled global source + reader XOR, rule #21).
__global__ __launch_bounds__(256, 2) void gemm_kernel(const unsigned short* __restrict__ Wb,
                                                      const unsigned short* __restrict__ XT,
                                                      float* __restrict__ out) {
    __shared__ __align__(16) char smA[4 * 8192];   // 4 x (128 rows x 64 B)
    __shared__ __align__(16) char smB[4 * 8192];

    int f = blockIdx.x;
    int xcd = f & 7;
    int local = f >> 3;            // 0..127
    int bz = local & 3;
    int lt = local >> 2;           // 0..31
    int bx = (xcd & 3) * 4 + (lt & 3);     // 0..15
    int by = (xcd >> 2) * 8 + (lt >> 2);   // 0..15

    int t = threadIdx.x;
    int w = t >> 6;                // 0..3
    int l = t & 63;
    int lane16 = l & 15;
    int quad = l >> 4;
    int wr = w >> 1;               // 0..1  (m-half)
    int wc = w & 1;                // 0..1  (n-half)
    int m0 = by * BM;
    int n0 = bx * BN;
    int ks = bz * KSLAB;

    f32x4 acc[4][4] = {};

    // ---- staging map (R6-identical): wave w covers rows w*32..w*32+31
    //      (2 calls x 16 rows); lane l -> row w*32 + c*16 + (l>>2), chunk l&3.
    //      Pre-swizzled source chunk: (l&3) ^ ((row>>1)&3) = (l&3)^((l>>3)&3).
    int rowS = w * 32 + (l >> 2);
    int lc   = (l & 3) ^ ((l >> 3) & 3);
    const unsigned short* gA0 = Wb + (long long)(m0 + rowS) * K_DIM + ks + lc * 8;
    const unsigned short* gA1 = gA0 + 16LL * K_DIM;
    const unsigned short* gB0 = XT + (long long)(n0 + rowS) * K_DIM + ks + lc * 8;
    const unsigned short* gB1 = gB0 + 16LL * K_DIM;

#define STAGE(BUF, KOFF) do { \
        int bo_ = (BUF) * 8192 + w * 2048; \
        async16(gA0 + (KOFF), smA + bo_); \
        async16(gA1 + (KOFF), smA + bo_ + 1024); \
        async16(gB0 + (KOFF), smB + bo_); \
        async16(gB1 + (KOFF), smB + bo_ + 1024); \
    } while (0)

    // ---- reader-side swizzled row offsets (bytes within one 8 KB buffer) ----
    int swz = ((quad ^ ((lane16 >> 1) & 3)) << 4);
    int arow = (wr * 64 + lane16) * 64 + swz;
    int brow = (wc * 64 + lane16) * 64 + swz;

    // ---- prologue: stage K-steps 0,1,2 (12 loads), wait for step 0 ----
    STAGE(0, 0);
    STAGE(1, BK);
    STAGE(2, 2 * BK);
    WAIT_VM8();                    // 8 newest = steps 1,2 -> step 0 landed
    RAW_BARRIER();

    for (int s = 0; s < NSTEP; ++s) {
        if (s + 3 < NSTEP)
            STAGE((s + 3) & 3, (s + 3) * BK);

        int bo = (s & 3) * 8192;
        const char* Ab = smA + bo + arow;
        const char* Bb = smB + bo + brow;
        bf16x8 a0 = *(const bf16x8*)(Ab);
        bf16x8 a1 = *(const bf16x8*)(Ab + 1024);
        bf16x8 a2 = *(const bf16x8*)(Ab + 2048);
        bf16x8 a3 = *(const bf16x8*)(Ab + 3072);
        bf16x8 b0 = *(const bf16x8*)(Bb);
        bf16x8 b1 = *(const bf16x8*)(Bb + 1024);
        bf16x8 b2 = *(const bf16x8*)(Bb + 2048);
        bf16x8 b3 = *(const bf16x8*)(Bb + 3072);

        acc[0][0] = __builtin_amdgcn_mfma_f32_16x16x32_bf16(a0, b0, acc[0][0], 0, 0, 0);
        acc[0][1] = __builtin_amdgcn_mfma_f32_16x16x32_bf16(a0, b1, acc[0][1], 0, 0, 0);
        acc[0][2] = __builtin_amdgcn_mfma_f32_16x16x32_bf16(a0, b2, acc[0][2], 0, 0, 0);
        acc[0][3] = __builtin_amdgcn_mfma_f32_16x16x32_bf16(a0, b3, acc[0][3], 0, 0, 0);
        acc[1][0] = __builtin_amdgcn_mfma_f32_16x16x32_bf16(a1, b0, acc[1][0], 0, 0, 0);
        acc[1][1] = __builtin_amdgcn_mfma_f32_16x16x32_bf16(a1, b1, acc[1][1], 0, 0, 0);
        acc[1][2] = __builtin_amdgcn_mfma_f32_16x16x32_bf16(a1, b2, acc[1][2], 0, 0, 0);
        acc[1][3] = __builtin_amdgcn_mfma_f32_16x16x32_bf16(a1, b3, acc[1][3], 0, 0, 0);
        acc[2][0] = __builtin_amdgcn_mfma_f32_16x16x32_bf16(a2, b0, acc[2][0], 0, 0, 0);
        acc[2][1] = __builtin_amdgcn_mfma_f32_16x16x32_bf16(a2, b1, acc[2][1], 0, 0, 0);
        acc[2][2] = __builtin_amdgcn_mfma_f32_16x16x32_bf16(a2, b2, acc[2][2], 0, 0, 0);
        acc[2][3] = __builtin_amdgcn_mfma_f32_16x16x32_bf16(a2, b3, acc[2][3], 0, 0, 0);
        acc[3][0] = __builtin_amdgcn_mfma_f32_16x16x32_bf16(a3, b0, acc[3][0], 0, 0, 0);
        acc[3][1] = __builtin_amdgcn_mfma_f32_16x16x32_bf16(a3, b1, acc[3][1], 0, 0, 0);
        acc[3][2] = __builtin_amdgcn_mfma_f32_16x16x32_bf16(a3, b2, acc[3][2], 0, 0, 0);
        acc[3][3] = __builtin_amdgcn_mfma_f32_16x16x32_bf16(a3, b3, acc[3][3], 0, 0, 0);

        // single end-of-step sync: counted vmcnt + lgkm drain + barrier
        if (s + 3 < NSTEP) {
            WAIT_VM8();            // 8 newest = steps s+2,s+3 -> s+1 landed
        } else if (s + 3 == NSTEP) {
            WAIT_VM4();            // 4 newest = step s+2 -> s+1 landed
        } else if (s + 2 == NSTEP) {
            WAIT_VM0();            // last buffer landed
        }
        if (s + 1 < NSTEP) {
            LGKM0();               // this step's ds_reads done before buffer
            RAW_BARRIER();         // (s&3) is rewritten at step s+1
        }
    }
#undef STAGE

    // Epilogue: C/D layout col = lane&15, row = quad*4 + reg  [m89-verified]
#pragma unroll
    for (int j = 0; j < 4; ++j) {
        int n = n0 + wc * 64 + j * 16 + lane16;
        if (n >= N_REAL) continue;
#pragma unroll
        for (int i = 0; i < 4; ++i) {
            int mbase = m0 + wr * 64 + i * 16 + quad * 4;
#pragma unroll
            for (int r = 0; r < 4; ++r) {
                int m = mbase + r;
                if (m < M_REAL)
                    atomicAdd(&out[(long long)m * N_REAL + n], acc[i][j][r]);
            }
        }
    }
}

// ---------------------------------------------------------------------------
extern "C" void kernel_launch(void* const* d_in, const int* in_sizes, int n_in,
                              void* d_out, int out_size, void* d_ws, size_t ws_size,
                              hipStream_t stream) {
    const float* W    = (const float*)d_in[0];  // [2000][8192]
    const float* bias = (const float*)d_in[1];  // [2000]
    const float* X    = (const float*)d_in[2];  // [8192][2000]
    float* out = (float*)d_out;

    unsigned short* Wb = (unsigned short*)d_ws;                 // [2048][8192] bf16
    unsigned short* XT = Wb + (long long)M_PAD * K_DIM;         // [2048][8192] bf16

    prep_kernel<<<NB_W + NB_X + NB_I, 256, 0, stream>>>(W, X, bias, Wb, XT, out);

    gemm_kernel<<<(N_PAD / BN) * (M_PAD / BM) * SPLITK, 256, 0, stream>>>(Wb, XT, out);
}

// Round 11
// 257.351 us; speedup vs baseline: 1.2551x; 1.0831x over previous
//
#include <hip/hip_runtime.h>

#define K_DIM 8192
#define M_REAL 2000
#define N_REAL 2000
#define M_PAD 2048
#define N_PAD 2048

#define BM 256
#define BN 256
#define BK 32
#define SPLITK 4
#define KSLAB (K_DIM / SPLITK)   // 2048
#define NSTEP (KSLAB / BK)       // 64 K-steps per block

// fused prep block ranges
#define NB_W 1024
#define NB_X 2048
#define NB_I 256

typedef __bf16 bf16x8 __attribute__((ext_vector_type(8)));
typedef float f32x4 __attribute__((ext_vector_type(4)));
typedef float fvec4 __attribute__((ext_vector_type(4)));

#define RAW_BARRIER()  asm volatile("s_barrier" ::: "memory")
#define LGKM0()        asm volatile("s_waitcnt lgkmcnt(0)" ::: "memory")
#define WAIT_VM8()     asm volatile("s_waitcnt vmcnt(8)" ::: "memory")
#define WAIT_VM4()     asm volatile("s_waitcnt vmcnt(4)" ::: "memory")
#define WAIT_VM0()     asm volatile("s_waitcnt vmcnt(0)" ::: "memory")

__device__ __forceinline__ unsigned short f2bf(float f) {
    union { float f; unsigned u; } v; v.f = f;
    unsigned r = v.u + 0x7FFFu + ((v.u >> 16) & 1u);  // RNE; inputs are finite normals
    return (unsigned short)(r >> 16);
}

__device__ __forceinline__ unsigned pk2(float a, float b) {
    return (unsigned)f2bf(a) | ((unsigned)f2bf(b) << 16);
}

__device__ __forceinline__ void async16(const void* g, void* l) {
    __builtin_amdgcn_global_load_lds((__attribute__((address_space(1))) void*)(g),
                                     (__attribute__((address_space(3))) void*)(l),
                                     16, 0, 0);
}

// ---------------------------------------------------------------------------
// Fused prep (one dispatch) — measured near-roofline (~44 us for 212 MB):
//   blocks [0,1024):       W f32 -> Wb bf16 [2048][8192], grid-stride, 32B ld/16B st
//   blocks [1024,3072):    X [8192][2000] f32 -> XT bf16 [2048][8192] transpose,
//                          conflict-free LDS (row stride 65 words === 1 mod 32)
//   blocks [3072,3328):    out[m][n] = bias[n] (float4 stores, grid-stride)
__global__ __launch_bounds__(256) void prep_kernel(const float* __restrict__ W,
                                                   const float* __restrict__ X,
                                                   const float* __restrict__ bias,
                                                   unsigned short* __restrict__ Wb,
                                                   unsigned short* __restrict__ XT,
                                                   float* __restrict__ out) {
    __shared__ unsigned short T[64][130];
    int bid = blockIdx.x;
    if (bid < NB_W) {
        unsigned tid = bid * 256u + threadIdx.x;
#pragma unroll
        for (unsigned i = 0; i < 8; ++i) {
            unsigned e = (i * (1024u * 256u) + tid) * 8u;       // element index
            uint4 o = make_uint4(0u, 0u, 0u, 0u);
            if (e < (unsigned)(M_REAL * K_DIM)) {
                fvec4 f0 = __builtin_nontemporal_load((const fvec4*)(W + e));
                fvec4 f1 = __builtin_nontemporal_load((const fvec4*)(W + e + 4));
                o.x = pk2(f0.x, f0.y);
                o.y = pk2(f0.z, f0.w);
                o.z = pk2(f1.x, f1.y);
                o.w = pk2(f1.z, f1.w);
            }
            *(uint4*)(Wb + e) = o;
        }
    } else if (bid < NB_W + NB_X) {
        int b = bid - NB_W;
        int k0 = (b & 63) << 7;        // 0..8064 step 128
        int n0 = (b >> 6) << 6;        // 0..1984 step 64
        int t = threadIdx.x;
        int c = t & 15;
        int r = t >> 4;
        int nl = c << 2;               // local n base (x4)
        int n = n0 + nl;
        bool valid = (n < N_REAL);
#pragma unroll
        for (int p = 0; p < 4; ++p) {
            int kl = (r << 1) + (p << 5);
            fvec4 v0 = {0.f, 0.f, 0.f, 0.f};
            fvec4 v1 = {0.f, 0.f, 0.f, 0.f};
            if (valid) {
                v0 = __builtin_nontemporal_load((const fvec4*)(X + (k0 + kl) * N_REAL + n));
                v1 = __builtin_nontemporal_load((const fvec4*)(X + (k0 + kl + 1) * N_REAL + n));
            }
            *(unsigned*)&T[nl + 0][kl] = pk2(v0.x, v1.x);
            *(unsigned*)&T[nl + 1][kl] = pk2(v0.y, v1.y);
            *(unsigned*)&T[nl + 2][kl] = pk2(v0.z, v1.z);
            *(unsigned*)&T[nl + 3][kl] = pk2(v0.w, v1.w);
        }
        __syncthreads();
#pragma unroll
        for (int it = 0; it < 4; ++it) {
            int nl2 = r + (it << 4);
            int kl2 = c << 3;
            const unsigned* tp = (const unsigned*)&T[nl2][kl2];
            uint4 o;
            o.x = tp[0]; o.y = tp[1]; o.z = tp[2]; o.w = tp[3];
            *(uint4*)(XT + (((n0 + nl2) << 13) + k0 + kl2)) = o;
        }
    } else {
        const int total = M_REAL * (N_REAL / 4);   // 1,000,000 float4
        for (int i = (bid - NB_W - NB_X) * 256 + (int)threadIdx.x; i < total; i += NB_I * 256) {
            int m = i / (N_REAL / 4);
            int n4 = i - m * (N_REAL / 4);
            float4 bv = *(const float4*)(bias + (n4 << 2));
            *(float4*)(out + m * N_REAL + (n4 << 2)) = bv;
        }
    }
}

// ---------------------------------------------------------------------------
// Split-K GEMM (R4 configuration — session-best, 256.39 us total, gemm
// 112.0 us, SQ_LDS_BANK_CONFLICT == 0):
// 256x256 tile, BK=32, 4-deep LDS pipeline (128 KiB), phase-interleaved
// schedule (T3+T4): per K-step two phases, each
//   { ds_read frags | 2x global_load_lds (step s+3) | barrier | lgkmcnt(0) |
//     setprio(1) 16x MFMA setprio(0) | barrier }
// Counted vmcnt(8) once per K-step (never 0 in main loop); tail peels 4->0.
//
// T2 swizzle: chunk ^= (row>>1)&3. Bank-slot = (row&1, chunk):
// (row&1, q^((row>>1)&3)) is a bijection per 8-row group -> 8 slots,
// 2 rows/slot = 2-way = free [R4-verified: SQ_LDS_BANK_CONFLICT == 0].
// Applied BOTH sides (rule #21): pre-swizzled global source + reader XOR.
//
// Race-freedom: buffer written at step s is (s+3)&3 == (s-1)&3, last read at
// step s-1; every wave's reads completed before s-1's final barrier
// (lgkmcnt(0) precedes MFMA precedes barrier), and stores issue after it.
// vmcnt(8): the 8 newest loads are exactly steps s+2,s+3 -> step s+1 landed.
__global__ __launch_bounds__(512, 2) void gemm_kernel(const unsigned short* __restrict__ Wb,
                                                      const unsigned short* __restrict__ XT,
                                                      float* __restrict__ out) {
    __shared__ __align__(16) unsigned short As[4][BM * BK];  // 4 x 16 KB
    __shared__ __align__(16) unsigned short Bs[4][BN * BK];  // 4 x 16 KB

    int f = blockIdx.x;
    int xcd = f & 7;
    int local = f >> 3;                    // 0..31
    int bz = local & 3;
    int bx = (xcd & 3) * 2 + ((local >> 2) & 1);   // 0..7
    int by = (xcd >> 2) * 4 + (local >> 3);        // 0..7

    int t = threadIdx.x;
    int w = t >> 6;              // 0..7
    int l = t & 63;
    int wm = (w >> 2) * 128;     // 0 or 128
    int wn = (w & 3) * 64;       // 0,64,128,192
    int lane16 = l & 15;
    int quad = l >> 4;
    int m0 = by * BM;
    int n0 = bx * BN;
    int ks = bz * KSLAB;

    f32x4 acc[8][4] = {};

    // ---- staging source pointers (pre-swizzled chunk within each 64B row) ----
    int rlin = t >> 2;                       // 0..127 (round-0 row; round1 = +128)
    int ck = (t & 3) ^ ((rlin >> 1) & 3);    // 16B chunk index, swizzled (T2)
    const unsigned short* gA0 = Wb + (long long)(m0 + rlin) * K_DIM + ks + ck * 8;
    const unsigned short* gA1 = gA0 + 128LL * K_DIM;
    const unsigned short* gB0 = XT + (long long)(n0 + rlin) * K_DIM + ks + ck * 8;
    const unsigned short* gB1 = gB0 + 128LL * K_DIM;

    char* smA = (char*)&As[0][0];
    char* smB = (char*)&Bs[0][0];
    int wslot = w * 1024;                    // wave-uniform LDS slot within a round

#define STAGE_A(OFF) do { \
        async16(gA0, smA + (OFF) + wslot); \
        async16(gA1, smA + (OFF) + 8192 + wslot); \
        gA0 += BK; gA1 += BK; } while (0)
#define STAGE_B(OFF) do { \
        async16(gB0, smB + (OFF) + wslot); \
        async16(gB1, smB + (OFF) + 8192 + wslot); \
        gB0 += BK; gB1 += BK; } while (0)

    // ---- reader-side swizzled row offsets (bytes within one 16 KB buffer) ----
    // row mod 8 == lane16 mod 8 for every frag (frag strides are 16 rows),
    // so (row>>1)&3 == (lane16>>1)&3.
    int swz = ((quad ^ ((lane16 >> 1) & 3)) << 4);   // 16B chunk swizzle (T2)
    int arow = (wm + lane16) * 64 + swz;
    int brow = (wn + lane16) * 64 + swz;

    // ---- prologue: stage K-steps 0,1,2 (12 loads), wait for step 0 ----
    STAGE_A(0);     STAGE_B(0);
    STAGE_A(16384); STAGE_B(16384);
    STAGE_A(32768); STAGE_B(32768);
    WAIT_VM8();                      // 8 newest = steps 1,2 -> step 0 landed
    RAW_BARRIER();

    int cur = 0;
    int stg = 49152;

    bf16x8 a0, a1, a2, a3, b0, b1, b2, b3;

    for (int s = 0; s < NSTEP; ++s) {
        // ---------------- phase 1: i0-3 x j0-3 ----------------
        {
            const char* ab = smA + cur + arow;
            const char* bb = smB + cur + brow;
            a0 = *(const bf16x8*)(ab);
            a1 = *(const bf16x8*)(ab + 1024);
            a2 = *(const bf16x8*)(ab + 2048);
            a3 = *(const bf16x8*)(ab + 3072);
            b0 = *(const bf16x8*)(bb);
            b1 = *(const bf16x8*)(bb + 1024);
            b2 = *(const bf16x8*)(bb + 2048);
            b3 = *(const bf16x8*)(bb + 3072);
            if (s < NSTEP - 3) STAGE_A(stg);
            RAW_BARRIER();
            LGKM0();
            __builtin_amdgcn_s_setprio(1);
            acc[0][0] = __builtin_amdgcn_mfma_f32_16x16x32_bf16(a0, b0, acc[0][0], 0, 0, 0);
            acc[0][1] = __builtin_amdgcn_mfma_f32_16x16x32_bf16(a0, b1, acc[0][1], 0, 0, 0);
            acc[0][2] = __builtin_amdgcn_mfma_f32_16x16x32_bf16(a0, b2, acc[0][2], 0, 0, 0);
            acc[0][3] = __builtin_amdgcn_mfma_f32_16x16x32_bf16(a0, b3, acc[0][3], 0, 0, 0);
            acc[1][0] = __builtin_amdgcn_mfma_f32_16x16x32_bf16(a1, b0, acc[1][0], 0, 0, 0);
            acc[1][1] = __builtin_amdgcn_mfma_f32_16x16x32_bf16(a1, b1, acc[1][1], 0, 0, 0);
            acc[1][2] = __builtin_amdgcn_mfma_f32_16x16x32_bf16(a1, b2, acc[1][2], 0, 0, 0);
            acc[1][3] = __builtin_amdgcn_mfma_f32_16x16x32_bf16(a1, b3, acc[1][3], 0, 0, 0);
            acc[2][0] = __builtin_amdgcn_mfma_f32_16x16x32_bf16(a2, b0, acc[2][0], 0, 0, 0);
            acc[2][1] = __builtin_amdgcn_mfma_f32_16x16x32_bf16(a2, b1, acc[2][1], 0, 0, 0);
            acc[2][2] = __builtin_amdgcn_mfma_f32_16x16x32_bf16(a2, b2, acc[2][2], 0, 0, 0);
            acc[2][3] = __builtin_amdgcn_mfma_f32_16x16x32_bf16(a2, b3, acc[2][3], 0, 0, 0);
            acc[3][0] = __builtin_amdgcn_mfma_f32_16x16x32_bf16(a3, b0, acc[3][0], 0, 0, 0);
            acc[3][1] = __builtin_amdgcn_mfma_f32_16x16x32_bf16(a3, b1, acc[3][1], 0, 0, 0);
            acc[3][2] = __builtin_amdgcn_mfma_f32_16x16x32_bf16(a3, b2, acc[3][2], 0, 0, 0);
            acc[3][3] = __builtin_amdgcn_mfma_f32_16x16x32_bf16(a3, b3, acc[3][3], 0, 0, 0);
            __builtin_amdgcn_s_setprio(0);
            RAW_BARRIER();
        }
        // ---------------- phase 2: i4-7 x j0-3 ----------------
        {
            const char* ab = smA + cur + arow + 4096;
            a0 = *(const bf16x8*)(ab);
            a1 = *(const bf16x8*)(ab + 1024);
            a2 = *(const bf16x8*)(ab + 2048);
            a3 = *(const bf16x8*)(ab + 3072);
            if (s < NSTEP - 3) {
                STAGE_B(stg);
                WAIT_VM8();          // 8 newest = steps s+2,s+3 -> s+1 landed
            } else if (s == NSTEP - 3) {
                WAIT_VM4();          // 4 newest = step 63 -> step 62 landed
            } else if (s == NSTEP - 2) {
                WAIT_VM0();          // step 63 landed
            }
            RAW_BARRIER();
            LGKM0();
            __builtin_amdgcn_s_setprio(1);
            acc[4][0] = __builtin_amdgcn_mfma_f32_16x16x32_bf16(a0, b0, acc[4][0], 0, 0, 0);
            acc[4][1] = __builtin_amdgcn_mfma_f32_16x16x32_bf16(a0, b1, acc[4][1], 0, 0, 0);
            acc[4][2] = __builtin_amdgcn_mfma_f32_16x16x32_bf16(a0, b2, acc[4][2], 0, 0, 0);
            acc[4][3] = __builtin_amdgcn_mfma_f32_16x16x32_bf16(a0, b3, acc[4][3], 0, 0, 0);
            acc[5][0] = __builtin_amdgcn_mfma_f32_16x16x32_bf16(a1, b0, acc[5][0], 0, 0, 0);
            acc[5][1] = __builtin_amdgcn_mfma_f32_16x16x32_bf16(a1, b1, acc[5][1], 0, 0, 0);
            acc[5][2] = __builtin_amdgcn_mfma_f32_16x16x32_bf16(a1, b2, acc[5][2], 0, 0, 0);
            acc[5][3] = __builtin_amdgcn_mfma_f32_16x16x32_bf16(a1, b3, acc[5][3], 0, 0, 0);
            acc[6][0] = __builtin_amdgcn_mfma_f32_16x16x32_bf16(a2, b0, acc[6][0], 0, 0, 0);
            acc[6][1] = __builtin_amdgcn_mfma_f32_16x16x32_bf16(a2, b1, acc[6][1], 0, 0, 0);
            acc[6][2] = __builtin_amdgcn_mfma_f32_16x16x32_bf16(a2, b2, acc[6][2], 0, 0, 0);
            acc[6][3] = __builtin_amdgcn_mfma_f32_16x16x32_bf16(a2, b3, acc[6][3], 0, 0, 0);
            acc[7][0] = __builtin_amdgcn_mfma_f32_16x16x32_bf16(a3, b0, acc[7][0], 0, 0, 0);
            acc[7][1] = __builtin_amdgcn_mfma_f32_16x16x32_bf16(a3, b1, acc[7][1], 0, 0, 0);
            acc[7][2] = __builtin_amdgcn_mfma_f32_16x16x32_bf16(a3, b2, acc[7][2], 0, 0, 0);
            acc[7][3] = __builtin_amdgcn_mfma_f32_16x16x32_bf16(a3, b3, acc[7][3], 0, 0, 0);
            __builtin_amdgcn_s_setprio(0);
            RAW_BARRIER();
        }
        cur = (cur + 16384) & 65535;
        stg = (stg + 16384) & 65535;
    }
#undef STAGE_A
#undef STAGE_B

    // Epilogue: C/D layout col = lane&15, row = quad*4 + reg  [m89-verified]
#pragma unroll
    for (int j = 0; j < 4; ++j) {
        int n = n0 + wn + j * 16 + lane16;
        if (n >= N_REAL) continue;
#pragma unroll
        for (int i = 0; i < 8; ++i) {
            int mbase = m0 + wm + i * 16 + quad * 4;
#pragma unroll
            for (int r = 0; r < 4; ++r) {
                int m = mbase + r;
                if (m < M_REAL)
                    atomicAdd(&out[(long long)m * N_REAL + n], acc[i][j][r]);
            }
        }
    }
}

// ---------------------------------------------------------------------------
extern "C" void kernel_launch(void* const* d_in, const int* in_sizes, int n_in,
                              void* d_out, int out_size, void* d_ws, size_t ws_size,
                              hipStream_t stream) {
    const float* W    = (const float*)d_in[0];  // [2000][8192]
    const float* bias = (const float*)d_in[1];  // [2000]
    const float* X    = (const float*)d_in[2];  // [8192][2000]
    float* out = (float*)d_out;

    unsigned short* Wb = (unsigned short*)d_ws;                 // [2048][8192] bf16
    unsigned short* XT = Wb + (long long)M_PAD * K_DIM;         // [2048][8192] bf16

    prep_kernel<<<NB_W + NB_X + NB_I, 256, 0, stream>>>(W, X, bias, Wb, XT, out);

    gemm_kernel<<<(N_PAD / BN) * (M_PAD / BM) * SPLITK, 512, 0, stream>>>(Wb, XT, out);
}

// Round 12
// 252.500 us; speedup vs baseline: 1.2792x; 1.0192x over previous
//
#include <hip/hip_runtime.h>

#define K_DIM 8192
#define M_REAL 2000
#define N_REAL 2000
#define M_PAD 2048
#define N_PAD 2048

#define BM 128
#define BN 128
#define BK 32
#define SPLITK 2
#define KSLAB (K_DIM / SPLITK)   // 4096
#define NSTEP (KSLAB / BK)       // 128 K-steps per block

// fused prep block ranges
#define NB_W 1024
#define NB_X 2048
#define NB_I 256

typedef __bf16 bf16x8 __attribute__((ext_vector_type(8)));
typedef float f32x4 __attribute__((ext_vector_type(4)));
typedef float fvec4 __attribute__((ext_vector_type(4)));

__device__ __forceinline__ unsigned short f2bf(float f) {
    union { float f; unsigned u; } v; v.f = f;
    unsigned r = v.u + 0x7FFFu + ((v.u >> 16) & 1u);  // RNE; inputs are finite normals
    return (unsigned short)(r >> 16);
}

__device__ __forceinline__ unsigned pk2(float a, float b) {
    return (unsigned)f2bf(a) | ((unsigned)f2bf(b) << 16);
}

__device__ __forceinline__ void async16(const void* g, void* l) {
    __builtin_amdgcn_global_load_lds((__attribute__((address_space(1))) void*)(g),
                                     (__attribute__((address_space(3))) void*)(l),
                                     16, 0, 0);
}

// ---------------------------------------------------------------------------
// Fused prep (one dispatch) — UNCHANGED (measured near-roofline ~44 us):
//   blocks [0,1024):       W f32 -> Wb bf16 [2048][8192], grid-stride, 32B ld/16B st
//   blocks [1024,3072):    X [8192][2000] f32 -> XT bf16 [2048][8192] transpose,
//                          conflict-free LDS (row stride 65 words === 1 mod 32)
//   blocks [3072,3328):    out[m][n] = bias[n] (float4 stores, grid-stride)
__global__ __launch_bounds__(256) void prep_kernel(const float* __restrict__ W,
                                                   const float* __restrict__ X,
                                                   const float* __restrict__ bias,
                                                   unsigned short* __restrict__ Wb,
                                                   unsigned short* __restrict__ XT,
                                                   float* __restrict__ out) {
    __shared__ unsigned short T[64][130];
    int bid = blockIdx.x;
    if (bid < NB_W) {
        unsigned tid = bid * 256u + threadIdx.x;
#pragma unroll
        for (unsigned i = 0; i < 8; ++i) {
            unsigned e = (i * (1024u * 256u) + tid) * 8u;       // element index
            uint4 o = make_uint4(0u, 0u, 0u, 0u);
            if (e < (unsigned)(M_REAL * K_DIM)) {
                fvec4 f0 = __builtin_nontemporal_load((const fvec4*)(W + e));
                fvec4 f1 = __builtin_nontemporal_load((const fvec4*)(W + e + 4));
                o.x = pk2(f0.x, f0.y);
                o.y = pk2(f0.z, f0.w);
                o.z = pk2(f1.x, f1.y);
                o.w = pk2(f1.z, f1.w);
            }
            *(uint4*)(Wb + e) = o;
        }
    } else if (bid < NB_W + NB_X) {
        int b = bid - NB_W;
        int k0 = (b & 63) << 7;        // 0..8064 step 128
        int n0 = (b >> 6) << 6;        // 0..1984 step 64
        int t = threadIdx.x;
        int c = t & 15;
        int r = t >> 4;
        int nl = c << 2;               // local n base (x4)
        int n = n0 + nl;
        bool valid = (n < N_REAL);
#pragma unroll
        for (int p = 0; p < 4; ++p) {
            int kl = (r << 1) + (p << 5);
            fvec4 v0 = {0.f, 0.f, 0.f, 0.f};
            fvec4 v1 = {0.f, 0.f, 0.f, 0.f};
            if (valid) {
                v0 = __builtin_nontemporal_load((const fvec4*)(X + (k0 + kl) * N_REAL + n));
                v1 = __builtin_nontemporal_load((const fvec4*)(X + (k0 + kl + 1) * N_REAL + n));
            }
            *(unsigned*)&T[nl + 0][kl] = pk2(v0.x, v1.x);
            *(unsigned*)&T[nl + 1][kl] = pk2(v0.y, v1.y);
            *(unsigned*)&T[nl + 2][kl] = pk2(v0.z, v1.z);
            *(unsigned*)&T[nl + 3][kl] = pk2(v0.w, v1.w);
        }
        __syncthreads();
#pragma unroll
        for (int it = 0; it < 4; ++it) {
            int nl2 = r + (it << 4);
            int kl2 = c << 3;
            const unsigned* tp = (const unsigned*)&T[nl2][kl2];
            uint4 o;
            o.x = tp[0]; o.y = tp[1]; o.z = tp[2]; o.w = tp[3];
            *(uint4*)(XT + (((n0 + nl2) << 13) + k0 + kl2)) = o;
        }
    } else {
        const int total = M_REAL * (N_REAL / 4);   // 1,000,000 float4
        for (int i = (bid - NB_W - NB_X) * 256 + (int)threadIdx.x; i < total; i += NB_I * 256) {
            int m = i / (N_REAL / 4);
            int n4 = i - m * (N_REAL / 4);
            float4 bv = *(const float4*)(bias + (n4 << 2));
            *(float4*)(out + m * N_REAL + (n4 << 2)) = bv;
        }
    }
}

// ---------------------------------------------------------------------------
// R12 GEMM: R6's kernel with SPLITK 4 -> 2. Theory: across all 7 gemm
// variants, dur == hbm_bytes / 1.45 TB/s (R2/R4/R6: 165 MB -> 112-116 us;
// R9: 283 -> 194; R10: 194 -> 134). The schedule was never the lever --
// BYTES are. SPLITK=2 halves the atomic RMW traffic (write 62.5 -> 31.3 MB,
// RMW fills ~31 -> ~16 MB): predicted ~114 MB -> 79-95 us.
// Grid 16x16x2 = 512 = 2 blocks/CU (avoids R7's 1-blk/CU latency collapse;
// R6's syncthreads-drain loop relies on cross-block TLP).
//
// K-loop unchanged from R6: 128x128 tile, BK=32, 256 thr (4 waves, 64x64
// wave-tiles), 2-deep LDS (32 KiB), global_load_lds with pre-swizzled
// source, 0-conflict T2 swizzle [R4-verified], __syncthreads per step.
__global__ __launch_bounds__(256, 4) void gemm_kernel(const unsigned short* __restrict__ Wb,
                                                      const unsigned short* __restrict__ XT,
                                                      float* __restrict__ out) {
    __shared__ __align__(16) char smA[2 * 8192];   // 2 x (128 rows x 64 B)
    __shared__ __align__(16) char smB[2 * 8192];

    int f = blockIdx.x;                    // 0..511
    int xcd = f & 7;
    int local = f >> 3;                    // 0..63
    int bz = local & 1;
    int lt = local >> 1;                   // 0..31
    int bx = (xcd & 3) * 4 + (lt & 3);     // 0..15
    int by = (xcd >> 2) * 8 + (lt >> 2);   // 0..15

    int t = threadIdx.x;
    int w = t >> 6;                // 0..3
    int l = t & 63;
    int lane16 = l & 15;
    int quad = l >> 4;
    int wr = w >> 1;               // 0..1  (m-half)
    int wc = w & 1;                // 0..1  (n-half)
    int m0 = by * BM;
    int n0 = bx * BN;
    int ks = bz * KSLAB;

    f32x4 acc[4][4] = {};

    // ---- staging map: wave w covers rows w*32..w*32+31 (2 calls x 16 rows);
    //      lane l -> row w*32 + c*16 + (l>>2), phys chunk l&3.
    //      Pre-swizzled source logical chunk: (l&3) ^ ((row>>1)&3) with
    //      (row>>1)&3 == (l>>3)&3 for both calls.
    int rowS = w * 32 + (l >> 2);
    int lc   = (l & 3) ^ ((l >> 3) & 3);
    const unsigned short* gA0 = Wb + (long long)(m0 + rowS) * K_DIM + ks + lc * 8;
    const unsigned short* gA1 = gA0 + 16LL * K_DIM;
    const unsigned short* gB0 = XT + (long long)(n0 + rowS) * K_DIM + ks + lc * 8;
    const unsigned short* gB1 = gB0 + 16LL * K_DIM;

#define STAGE(BUF, KOFF) do { \
        int bo_ = (BUF) * 8192 + w * 2048; \
        async16(gA0 + (KOFF), smA + bo_); \
        async16(gA1 + (KOFF), smA + bo_ + 1024); \
        async16(gB0 + (KOFF), smB + bo_); \
        async16(gB1 + (KOFF), smB + bo_ + 1024); \
    } while (0)

    // ---- reader-side swizzled row offsets (bytes within one 8 KB buffer) ----
    int swz = ((quad ^ ((lane16 >> 1) & 3)) << 4);
    int arow = (wr * 64 + lane16) * 64 + swz;
    int brow = (wc * 64 + lane16) * 64 + swz;

    // ---- prologue ----
    STAGE(0, 0);
    __syncthreads();

    for (int s = 0; s < NSTEP; ++s) {
        if (s + 1 < NSTEP)
            STAGE((s + 1) & 1, (s + 1) * BK);

        int bo = (s & 1) * 8192;
        const char* Ab = smA + bo + arow;
        const char* Bb = smB + bo + brow;
        bf16x8 a0 = *(const bf16x8*)(Ab);
        bf16x8 a1 = *(const bf16x8*)(Ab + 1024);
        bf16x8 a2 = *(const bf16x8*)(Ab + 2048);
        bf16x8 a3 = *(const bf16x8*)(Ab + 3072);
        bf16x8 b0 = *(const bf16x8*)(Bb);
        bf16x8 b1 = *(const bf16x8*)(Bb + 1024);
        bf16x8 b2 = *(const bf16x8*)(Bb + 2048);
        bf16x8 b3 = *(const bf16x8*)(Bb + 3072);

        acc[0][0] = __builtin_amdgcn_mfma_f32_16x16x32_bf16(a0, b0, acc[0][0], 0, 0, 0);
        acc[0][1] = __builtin_amdgcn_mfma_f32_16x16x32_bf16(a0, b1, acc[0][1], 0, 0, 0);
        acc[0][2] = __builtin_amdgcn_mfma_f32_16x16x32_bf16(a0, b2, acc[0][2], 0, 0, 0);
        acc[0][3] = __builtin_amdgcn_mfma_f32_16x16x32_bf16(a0, b3, acc[0][3], 0, 0, 0);
        acc[1][0] = __builtin_amdgcn_mfma_f32_16x16x32_bf16(a1, b0, acc[1][0], 0, 0, 0);
        acc[1][1] = __builtin_amdgcn_mfma_f32_16x16x32_bf16(a1, b1, acc[1][1], 0, 0, 0);
        acc[1][2] = __builtin_amdgcn_mfma_f32_16x16x32_bf16(a1, b2, acc[1][2], 0, 0, 0);
        acc[1][3] = __builtin_amdgcn_mfma_f32_16x16x32_bf16(a1, b3, acc[1][3], 0, 0, 0);
        acc[2][0] = __builtin_amdgcn_mfma_f32_16x16x32_bf16(a2, b0, acc[2][0], 0, 0, 0);
        acc[2][1] = __builtin_amdgcn_mfma_f32_16x16x32_bf16(a2, b1, acc[2][1], 0, 0, 0);
        acc[2][2] = __builtin_amdgcn_mfma_f32_16x16x32_bf16(a2, b2, acc[2][2], 0, 0, 0);
        acc[2][3] = __builtin_amdgcn_mfma_f32_16x16x32_bf16(a2, b3, acc[2][3], 0, 0, 0);
        acc[3][0] = __builtin_amdgcn_mfma_f32_16x16x32_bf16(a3, b0, acc[3][0], 0, 0, 0);
        acc[3][1] = __builtin_amdgcn_mfma_f32_16x16x32_bf16(a3, b1, acc[3][1], 0, 0, 0);
        acc[3][2] = __builtin_amdgcn_mfma_f32_16x16x32_bf16(a3, b2, acc[3][2], 0, 0, 0);
        acc[3][3] = __builtin_amdgcn_mfma_f32_16x16x32_bf16(a3, b3, acc[3][3], 0, 0, 0);

        if (s + 1 < NSTEP)
            __syncthreads();       // drains vmcnt/lgkm + barrier (R6 semantics)
    }
#undef STAGE

    // Epilogue: C/D layout col = lane&15, row = quad*4 + reg  [m89-verified]
#pragma unroll
    for (int j = 0; j < 4; ++j) {
        int n = n0 + wc * 64 + j * 16 + lane16;
        if (n >= N_REAL) continue;
#pragma unroll
        for (int i = 0; i < 4; ++i) {
            int mbase = m0 + wr * 64 + i * 16 + quad * 4;
#pragma unroll
            for (int r = 0; r < 4; ++r) {
                int m = mbase + r;
                if (m < M_REAL)
                    atomicAdd(&out[(long long)m * N_REAL + n], acc[i][j][r]);
            }
        }
    }
}

// ---------------------------------------------------------------------------
extern "C" void kernel_launch(void* const* d_in, const int* in_sizes, int n_in,
                              void* d_out, int out_size, void* d_ws, size_t ws_size,
                              hipStream_t stream) {
    const float* W    = (const float*)d_in[0];  // [2000][8192]
    const float* bias = (const float*)d_in[1];  // [2000]
    const float* X    = (const float*)d_in[2];  // [8192][2000]
    float* out = (float*)d_out;

    unsigned short* Wb = (unsigned short*)d_ws;                 // [2048][8192] bf16
    unsigned short* XT = Wb + (long long)M_PAD * K_DIM;         // [2048][8192] bf16

    prep_kernel<<<NB_W + NB_X + NB_I, 256, 0, stream>>>(W, X, bias, Wb, XT, out);

    gemm_kernel<<<(N_PAD / BN) * (M_PAD / BM) * SPLITK, 256, 0, stream>>>(Wb, XT, out);
}